// Round 1
// baseline (23305.588 us; speedup 1.0000x reference)
//
#include <hip/hip_runtime.h>
#include <math.h>

// Problem constants (from reference)
#define H_ 270
#define W_ 480
#define HW_ (H_ * W_)            // 129600
#define C_ 512
#define NC_ 19
#define N_ 32400
#define NP_ 32512                // N padded to multiple of 128
#define FULLPIX 2073600          // 1080*1920
#define K_ 9

// GEMM tiling
#define BM 64
#define BN 128
#define BK 16
#define TM 4
#define TN 8

static_assert(NP_ % BN == 0, "pad");
static_assert(NP_ % BM == 0, "pad");
static_assert(C_ % BK == 0, "pad");

// ---------------------------------------------------------------------------
// Kernel A: gather sampled pixels into MT[C][NP] (K-major, coalesced writes).
// grid (NP/256, C), block 256
__global__ void gather_kernel(const float* __restrict__ feat,
                              const int* __restrict__ sidx,
                              float* __restrict__ MT) {
    int i = blockIdx.x * 256 + threadIdx.x;   // 0..NP-1
    int c = blockIdx.y;
    float v = 0.0f;
    if (i < N_) v = feat[(size_t)c * HW_ + sidx[i]];
    MT[(size_t)c * NP_ + i] = v;
}

// ---------------------------------------------------------------------------
// Kernel B: per-sample squared norm. Pad entries get 1e30 (never selected).
// grid NP/256, block 256
__global__ void sq_kernel(const float* __restrict__ MT, float* __restrict__ fsq) {
    int i = blockIdx.x * 256 + threadIdx.x;
    float s = 0.0f;
    for (int c = 0; c < C_; ++c) {
        float v = MT[(size_t)c * NP_ + i];
        s = fmaf(v, v, s);
    }
    fsq[i] = (i < N_) ? s : 1e30f;
}

// ---------------------------------------------------------------------------
// Kernel C: predicted class = argmax over 19 channels (first-max like jnp.argmax)
// grid NP/256, block 256
__global__ void cls_kernel(const float* __restrict__ outs,
                           const int* __restrict__ sidx,
                           int* __restrict__ cls) {
    int i = blockIdx.x * 256 + threadIdx.x;
    if (i >= NP_) return;
    if (i >= N_) { cls[i] = 0; return; }
    int p = sidx[i];
    float best = outs[p];
    int bk = 0;
#pragma unroll
    for (int k = 1; k < NC_; ++k) {
        float v = outs[(size_t)k * HW_ + p];
        if (v > best) { best = v; bk = k; }   // strict > keeps first max
    }
    cls[i] = bk;
}

// ---------------------------------------------------------------------------
// Kernel D: fused Gram-GEMM + per-row top-9 + neighbor-class entropy.
// grid NP/BM = 508 blocks, 256 threads (tx=tid&15 col-group, ty=tid>>4 row-group)
__launch_bounds__(256, 2)
__global__ void knn_kernel(const float* __restrict__ MT,
                           const float* __restrict__ fsq,
                           const int* __restrict__ cls,
                           const int* __restrict__ sidx,
                           float* __restrict__ out) {
    __shared__ float As[BK][BM];         // 4 KB
    __shared__ float Bs[BK][BN];         // 8 KB
    __shared__ float dT[BN][BM + 4];     // 34.8 KB; 68-word stride -> 2-way (free) scan reads

    const int tid = threadIdx.x;
    const int tx = tid & 15;
    const int ty = tid >> 4;
    const int ibase = blockIdx.x * BM;

    // Row-owner (tid<BM) top-9 lives entirely in registers, sorted ascending.
    float t9d[K_];
    int   t9i[K_];
#pragma unroll
    for (int s = 0; s < K_; ++s) { t9d[s] = 1e38f; t9i[s] = -1; }
    float w9 = 1e38f;   // cached 9th-best

    float si[TM];
#pragma unroll
    for (int m = 0; m < TM; ++m) si[m] = fsq[ibase + ty * TM + m];

    float acc[TM][TN];

    for (int jt = 0; jt < NP_ / BN; ++jt) {
        const int jbase = jt * BN;
#pragma unroll
        for (int m = 0; m < TM; ++m)
#pragma unroll
            for (int n = 0; n < TN; ++n) acc[m][n] = 0.0f;

        for (int ck = 0; ck < C_ / BK; ++ck) {
            const int cc = ck * BK;
            // stage A tile: 16x64 floats = 256 float4, one per thread
            {
                int kk = tid >> 4, seg = tid & 15;
                *(float4*)&As[kk][seg * 4] =
                    *(const float4*)&MT[(size_t)(cc + kk) * NP_ + ibase + seg * 4];
            }
            // stage B tile: 16x128 floats = 512 float4, two per thread
#pragma unroll
            for (int l = 0; l < 2; ++l) {
                int idx = tid + l * 256;
                int kk = idx >> 5, seg = idx & 31;
                *(float4*)&Bs[kk][seg * 4] =
                    *(const float4*)&MT[(size_t)(cc + kk) * NP_ + jbase + seg * 4];
            }
            __syncthreads();
#pragma unroll
            for (int kk = 0; kk < BK; ++kk) {
                float4 av  = *(const float4*)&As[kk][ty * TM];
                float4 bv0 = *(const float4*)&Bs[kk][tx * TN];
                float4 bv1 = *(const float4*)&Bs[kk][tx * TN + 4];
                float a[TM] = {av.x, av.y, av.z, av.w};
                float b[TN] = {bv0.x, bv0.y, bv0.z, bv0.w, bv1.x, bv1.y, bv1.z, bv1.w};
#pragma unroll
                for (int m = 0; m < TM; ++m)
#pragma unroll
                    for (int n = 0; n < TN; ++n)
                        acc[m][n] = fmaf(a[m], b[n], acc[m][n]);
            }
            __syncthreads();
        }

        // distances -> dT (transposed: dT[col][row]); same eval order as reference:
        // (sq_i - 2*dot) + sq_j, clamped at 1e-12
        float sj[TN];
#pragma unroll
        for (int n = 0; n < TN; ++n) sj[n] = fsq[jbase + tx * TN + n];
#pragma unroll
        for (int n = 0; n < TN; ++n) {
            float d0 = fmaxf(si[0] - 2.0f * acc[0][n] + sj[n], 1e-12f);
            float d1 = fmaxf(si[1] - 2.0f * acc[1][n] + sj[n], 1e-12f);
            float d2 = fmaxf(si[2] - 2.0f * acc[2][n] + sj[n], 1e-12f);
            float d3 = fmaxf(si[3] - 2.0f * acc[3][n] + sj[n], 1e-12f);
            *(float4*)&dT[tx * TN + n][ty * TM] = make_float4(d0, d1, d2, d3);
        }
        __syncthreads();

        // merge: one row-owner lane per row scans BN dists in ascending j order.
        // strict < displacement == jax.lax.top_k lower-index-wins tie rule.
        if (tid < BM) {
            int jlim = min(BN, N_ - jbase);   // drop padded columns on last tile
#pragma unroll 4
            for (int jj = 0; jj < jlim; ++jj) {
                float d = dT[jj][tid];
                if (d < w9) {
                    float cd = d;
                    int   ci = jbase + jj;
#pragma unroll
                    for (int s = 0; s < K_; ++s) {
                        if (cd < t9d[s]) {
                            float td = t9d[s]; t9d[s] = cd; cd = td;
                            int   ti = t9i[s]; t9i[s] = ci; ci = ti;
                        }
                    }
                    w9 = t9d[K_ - 1];
                }
            }
        }
        // no barrier needed: next tile's first __syncthreads orders dT reuse
    }

    // finalize: neighbor-class entropy
    if (tid < BM) {
        int i = ibase + tid;
        if (i < N_) {
            int nb[K_];
#pragma unroll
            for (int s = 0; s < K_; ++s) nb[s] = cls[t9i[s]];
            float ent = 0.0f;
#pragma unroll
            for (int k = 0; k < NC_; ++k) {
                int c = 0;
#pragma unroll
                for (int s = 0; s < K_; ++s) c += (nb[s] == k) ? 1 : 0;
                if (c > 0) {
                    float p = (float)c / 9.0f;
                    ent += -p * logf(p + 1e-6f);
                }
            }
            ent = ent / 2.9444389791664403f;   // np.float32(np.log(19))
            out[sidx[i]] = ent;
        }
    }
}

// ---------------------------------------------------------------------------
// Kernel E: prototype-distance rank score.
// grid NP/256, block 256
__global__ void proto_kernel(const float* __restrict__ MT,
                             const float* __restrict__ fsq,
                             const int* __restrict__ cls,
                             const int* __restrict__ sidx,
                             const float* __restrict__ protos,
                             float* __restrict__ out) {
    __shared__ float P[NC_][C_];    // 38 KB
    __shared__ float psq[NC_];
    int tid = threadIdx.x;
    for (int idx = tid; idx < NC_ * C_; idx += 256)
        P[idx >> 9][idx & (C_ - 1)] = protos[idx];
    __syncthreads();
    if (tid < NC_) {
        float s = 0.0f;
        for (int c = 0; c < C_; ++c) { float v = P[tid][c]; s = fmaf(v, v, s); }
        psq[tid] = s;
    }
    __syncthreads();

    int i = blockIdx.x * 256 + tid;
    if (i >= N_) return;

    float accp[NC_];
#pragma unroll
    for (int k = 0; k < NC_; ++k) accp[k] = 0.0f;
    for (int c = 0; c < C_; ++c) {
        float f = MT[(size_t)c * NP_ + i];   // coalesced across lanes
#pragma unroll
        for (int k = 0; k < NC_; ++k) accp[k] = fmaf(f, P[k][c], accp[k]);
    }
    float s = fsq[i];
    int ci = cls[i];
    float dp[NC_];
    float dc = 0.0f;
#pragma unroll
    for (int k = 0; k < NC_; ++k) {
        float v = fmaxf(s - 2.0f * accp[k] + psq[k], 1e-12f);
        dp[k] = v;
        if (k == ci) dc = v;       // avoid runtime-indexed array (rule #20)
    }
    // rank of predicted class under stable argsort by distance
    int rank = 0;
#pragma unroll
    for (int k = 0; k < NC_; ++k) {
        rank += (dp[k] < dc) ? 1 : 0;
        rank += ((k < ci) && (dp[k] == dc)) ? 1 : 0;
    }
    out[FULLPIX + sidx[i]] = (float)rank / 18.0f;
}

// ---------------------------------------------------------------------------
extern "C" void kernel_launch(void* const* d_in, const int* in_sizes, int n_in,
                              void* d_out, int out_size, void* d_ws, size_t ws_size,
                              hipStream_t stream) {
    const float* feat   = (const float*)d_in[0];   // [1,512,270,480]
    const float* outs   = (const float*)d_in[1];   // [1,19,270,480]
    const float* protos = (const float*)d_in[2];   // [1,19,512]
    const int*   sidx   = (const int*)d_in[3];     // [32400] sorted
    float* out = (float*)d_out;                    // 2 x 2073600 f32

    // workspace layout
    char* ws = (char*)d_ws;
    float* MT  = (float*)ws;                                   // 512*32512*4 = 66,584,576 B
    float* fsq = (float*)(ws + (size_t)66584576);              // 32512*4
    int*   cls = (int*)(ws + (size_t)66584576 + 130048);       // 32512*4

    // outputs are zero except at sampled positions
    hipMemsetAsync(d_out, 0, (size_t)2 * FULLPIX * sizeof(float), stream);

    gather_kernel<<<dim3(NP_ / 256, C_), 256, 0, stream>>>(feat, sidx, MT);
    sq_kernel<<<NP_ / 256, 256, 0, stream>>>(MT, fsq);
    cls_kernel<<<NP_ / 256, 256, 0, stream>>>(outs, sidx, cls);
    knn_kernel<<<NP_ / BM, 256, 0, stream>>>(MT, fsq, cls, sidx, out);
    proto_kernel<<<NP_ / 256, 256, 0, stream>>>(MT, fsq, cls, sidx, protos, out);
}